// Round 1
// baseline (32.950 us; speedup 1.0000x reference)
//
#include <hip/hip_runtime.h>
#include <math.h>

// Problem constants (mirror reference)
#define NPTS 350   // raw refractive_index samples
#define NSM  331   // after 'valid' conv with KS=20
#define KS   20    // gaussian kernel size
#define LAc  15    // layers above
#define LBc  15    // layers below
#define NFIX 32    // LA + LB + 2 fixed-n entries
#define NINT 31    // interior layers (above + unknown + below)
#define NW   2048
#define NA   128

// ---------------------------------------------------------------------------
// Prep: gaussian-smooth n(350)->331, then linear-interp onto the 2048
// simulation wavelengths (dyn grid is linspace(min_wl, max_wl, 331); the
// repeated-tail entries in the reference are all equal to the last value, so
// clamped linear interp on the 331-point grid is exactly equivalent).
// ---------------------------------------------------------------------------
__global__ void prep_kernel(const float* __restrict__ nk,
                            const float* __restrict__ wl,
                            float* __restrict__ n_unk_w) {
    __shared__ float kern[KS];
    __shared__ float nks[NPTS];
    __shared__ float nsm[NSM];
    const int tid = threadIdx.x;

    if (tid < KS) {
        float x = -10.0f + (float)tid * (20.0f / 19.0f);
        kern[tid] = expf(-(x * x) * (1.0f / 32.0f));  // amplitude cancels in norm
    }
    for (int i = tid; i < NPTS; i += blockDim.x) nks[i] = nk[i];
    __syncthreads();
    if (tid == 0) {
        float s = 0.0f;
        for (int j = 0; j < KS; ++j) s += kern[j];
        float inv = 1.0f / s;
        for (int j = 0; j < KS; ++j) kern[j] *= inv;
    }
    __syncthreads();
    for (int i = tid; i < NSM; i += blockDim.x) {
        float s = 0.0f;
#pragma unroll
        for (int j = 0; j < KS; ++j) s += nks[i + j] * kern[j];  // kern symmetric
        nsm[i] = s;
    }
    __syncthreads();
    const float l0 = wl[0], l1 = wl[NW - 1];           // linspace -> min/max
    const float scale = (float)(NSM - 1) / (l1 - l0);
    for (int w = tid; w < NW; w += blockDim.x) {
        float pos = (wl[w] - l0) * scale;
        pos = fminf(fmaxf(pos, 0.0f), (float)(NSM - 1));
        int i0 = (int)pos;
        if (i0 > NSM - 2) i0 = NSM - 2;
        float f = pos - (float)i0;
        n_unk_w[w] = nsm[i0] + f * (nsm[i0 + 1] - nsm[i0]);
    }
}

__device__ __forceinline__ float layer_n(int l, const float* fn, float nunk) {
    // layers: [0..LAc]=fixed[0..LAc], [LAc+1]=unknown, [LAc+2..32]=fixed[l-1]
    if (l <= LAc) return fn[l];
    if (l == LAc + 1) return nunk;
    return fn[l - 1];
}

// ---------------------------------------------------------------------------
// Main TMM kernel: one thread per (w,a). All n real, nsin<min(n) => q,r,t real.
// R = |M10/M00|^2 is invariant to real scaling of M, so the 1/t interface
// scale factors are dropped (no overflow: product of t's <~ 2e5).
// ---------------------------------------------------------------------------
__global__ __launch_bounds__(256) void tmm_kernel(
    const float* __restrict__ n_unk_w,
    const float* __restrict__ fixed_n,
    const float* __restrict__ d_above,
    const float* __restrict__ d_unk,
    const float* __restrict__ d_below,
    const float* __restrict__ wl,
    const float* __restrict__ angles,
    float* __restrict__ out) {
    __shared__ float fn[NFIX];
    __shared__ float dd[NINT];
    const int tid = threadIdx.x;
    if (tid < NFIX) fn[tid] = fixed_n[tid];
    if (tid < NINT) {
        float v;
        if (tid < LAc)       v = d_above[tid];
        else if (tid == LAc) v = d_unk[0];
        else                 v = d_below[tid - LAc - 1];
        dd[tid] = v;
    }
    __syncthreads();

    const int idx = blockIdx.x * blockDim.x + tid;
    const int w = idx >> 7;    // NA = 128
    const int a = idx & (NA - 1);

    const float lam  = wl[w];
    const float nunk = n_unk_w[w];
    const float nsin = fn[0] * sinf(angles[a]);
    const float nsin2 = nsin * nsin;
    const float k0 = 6.28318530717958647692f / lam;  // 2*pi/lambda

    // interface 0 (layer 0 -> 1); drop the 1/t scale.
    float q_cur;
    {
        const float n0 = fn[0];
        const float n1 = layer_n(1, fn, nunk);
        const float q0 = sqrtf(n0 * n0 - nsin2);
        q_cur = sqrtf(n1 * n1 - nsin2);
        const float r = (q0 - q_cur) / (q0 + q_cur);
        // M = [[1, r],[r, 1]] (times dropped scalar)
        // complex storage: rows (M00,M01) and (M10,M11)
        // initialized below
        float M00r = 1.0f, M00i = 0.0f, M01r = r, M01i = 0.0f;
        float M10r = r,    M10i = 0.0f, M11r = 1.0f, M11i = 0.0f;

#pragma unroll
        for (int j = 0; j < NINT; ++j) {
            const float delta = k0 * q_cur * dd[j];
            float s, c;
            sincosf(delta, &s, &c);
            // col0 *= e^{-i d}: (x)(c - i s) ; col1 *= e^{+i d}: (x)(c + i s)
            const float t0r = M00r * c + M00i * s, t0i = M00i * c - M00r * s;
            const float t2r = M10r * c + M10i * s, t2i = M10i * c - M10r * s;
            const float t1r = M01r * c - M01i * s, t1i = M01i * c + M01r * s;
            const float t3r = M11r * c - M11i * s, t3i = M11i * c + M11r * s;
            // next interface (layer j+1 -> j+2)
            const float nn = layer_n(j + 2, fn, nunk);
            const float q_next = sqrtf(nn * nn - nsin2);
            const float r2 = (q_cur - q_next) / (q_cur + q_next);
            // M = MP @ [[1, r2],[r2, 1]]  (1/t dropped)
            M00r = t0r + r2 * t1r;  M00i = t0i + r2 * t1i;
            M01r = r2 * t0r + t1r;  M01i = r2 * t0i + t1i;
            M10r = t2r + r2 * t3r;  M10i = t2i + r2 * t3i;
            M11r = r2 * t2r + t3r;  M11i = r2 * t2i + t3i;
            q_cur = q_next;
        }
        const float num = M10r * M10r + M10i * M10i;
        const float den = M00r * M00r + M00i * M00i;
        if (idx < NW * NA) out[idx] = num / den;
    }
}

extern "C" void kernel_launch(void* const* d_in, const int* in_sizes, int n_in,
                              void* d_out, int out_size, void* d_ws, size_t ws_size,
                              hipStream_t stream) {
    const float* nk       = (const float*)d_in[0];  // refractive_index [350]
    const float* d_unk    = (const float*)d_in[1];  // unknown_layer_thickness [1]
    const float* d_above  = (const float*)d_in[2];  // thickness_above [15]
    const float* d_below  = (const float*)d_in[3];  // thickness_below [15]
    const float* fixed_n  = (const float*)d_in[4];  // fixed_n [32]
    const float* wl       = (const float*)d_in[5];  // wavelengths [2048]
    const float* angles   = (const float*)d_in[6];  // angles [128]
    float* out = (float*)d_out;
    float* n_unk_w = (float*)d_ws;                  // 2048 floats scratch

    prep_kernel<<<1, 512, 0, stream>>>(nk, wl, n_unk_w);
    tmm_kernel<<<(NW * NA) / 256, 256, 0, stream>>>(n_unk_w, fixed_n, d_above,
                                                    d_unk, d_below, wl, angles, out);
}

// Round 2
// 18.007 us; speedup vs baseline: 1.8299x; 1.8299x over previous
//
#include <hip/hip_runtime.h>
#include <math.h>

// Problem constants (mirror reference)
#define NPTS 350   // raw refractive_index samples
#define NSM  331   // after 'valid' conv with KS=20
#define KS   20    // gaussian kernel size
#define LAc  15    // layers above
#define NFIX 32    // LA + LB + 2 fixed-n entries
#define NLAY 33    // total layers
#define NIF  32    // interfaces
#define NINT 31    // interior layers
#define NW   2048
#define NA   128

// d_ws layout (float offsets)
#define WS_NUNK 0                        // [NW]    n of unknown layer at sim wavelengths
#define WS_R    (NW)                     // [NIF*NA]  r per interface (rows 15,16 unused)
#define WS_QD2  (NW + NIF * NA)          // [NINT*NA] 2*q_{j+1}*d_j (row 15 unused)
#define WS_QA   (WS_QD2 + NINT * NA)     // [NA] q of layer 15
#define WS_QB   (WS_QA + NA)             // [NA] q of layer 17
#define WS_NS2  (WS_QB + NA)             // [NA] (n0 sin theta)^2

// ---------------------------------------------------------------------------
// Prep: (A) gaussian-smooth n(350)->331 + linear-interp onto the 2048 sim
// wavelengths; (B) per-angle tables: q_l(a), interface r's, 2*q*d phase
// coefficients. All n real and > nsin => q,r real throughout.
// ---------------------------------------------------------------------------
__global__ void prep_kernel(const float* __restrict__ nk,
                            const float* __restrict__ wl,
                            const float* __restrict__ fixed_n,
                            const float* __restrict__ d_above,
                            const float* __restrict__ d_below,
                            const float* __restrict__ angles,
                            float* __restrict__ ws) {
    __shared__ float kern[KS];
    __shared__ float nks[NPTS];
    __shared__ float nsm[NSM];
    const int tid = threadIdx.x;

    if (tid < KS) {
        float x = -10.0f + (float)tid * (20.0f / 19.0f);
        kern[tid] = expf(-(x * x) * (1.0f / 32.0f));  // amplitude cancels in norm
    }
    for (int i = tid; i < NPTS; i += blockDim.x) nks[i] = nk[i];
    __syncthreads();
    if (tid == 0) {
        float s = 0.0f;
        for (int j = 0; j < KS; ++j) s += kern[j];
        float inv = 1.0f / s;
        for (int j = 0; j < KS; ++j) kern[j] *= inv;
    }
    __syncthreads();
    for (int i = tid; i < NSM; i += blockDim.x) {
        float s = 0.0f;
#pragma unroll
        for (int j = 0; j < KS; ++j) s += nks[i + j] * kern[j];
        nsm[i] = s;
    }
    __syncthreads();
    const float l0 = wl[0], l1 = wl[NW - 1];
    const float scale = (float)(NSM - 1) / (l1 - l0);
    for (int w = tid; w < NW; w += blockDim.x) {
        float pos = (wl[w] - l0) * scale;
        pos = fminf(fmaxf(pos, 0.0f), (float)(NSM - 1));
        int i0 = (int)pos;
        if (i0 > NSM - 2) i0 = NSM - 2;
        float f = pos - (float)i0;
        ws[WS_NUNK + w] = nsm[i0] + f * (nsm[i0 + 1] - nsm[i0]);
    }

    // (B) per-angle tables
    if (tid < NA) {
        const float ang = angles[tid];
        const float nsin = fixed_n[0] * sinf(ang);
        const float ns2 = nsin * nsin;
        ws[WS_NS2 + tid] = ns2;
        float q[NLAY];
#pragma unroll
        for (int l = 0; l < NLAY; ++l) {
            if (l == LAc + 1) { q[l] = 0.0f; continue; }  // unknown layer
            float n = (l <= LAc) ? fixed_n[l] : fixed_n[l - 1];
            q[l] = sqrtf(n * n - ns2);
        }
        ws[WS_QA + tid] = q[LAc];       // layer 15
        ws[WS_QB + tid] = q[LAc + 2];   // layer 17
#pragma unroll
        for (int j = 0; j < NIF; ++j) {
            if (j == LAc || j == LAc + 1) continue;   // involve unknown layer
            ws[WS_R + j * NA + tid] = (q[j] - q[j + 1]) / (q[j] + q[j + 1]);
        }
#pragma unroll
        for (int j = 0; j < NINT; ++j) {
            if (j == LAc) continue;     // unknown layer phase is per-thread
            float dj = (j < LAc) ? d_above[j] : d_below[j - LAc - 1];
            ws[WS_QD2 + j * NA + tid] = 2.0f * q[j + 1] * dj;
        }
    }
}

// ---------------------------------------------------------------------------
// Main: one thread per (w,a). Backward recursive Fresnel:
//   rho_j = (r_j + rho_{j+1} e^{2 i delta_{j+1}}) / (1 + r_j rho_{j+1} e^{2 i delta_{j+1}})
// (== M10/M00 of the reference's matrix chain; 1/t scale factors cancel).
// Phases kept in revolutions: rev = 2 q d / lambda; v_fract + v_sin/v_cos.
// ---------------------------------------------------------------------------
__global__ __launch_bounds__(256) void tmm_kernel(
    const float* __restrict__ ws,
    const float* __restrict__ d_unk,
    const float* __restrict__ wl,
    float* __restrict__ out) {
    const int idx = blockIdx.x * blockDim.x + threadIdx.x;
    const int w = idx >> 7;        // NA = 128
    const int a = idx & (NA - 1);

    const float invlam = __builtin_amdgcn_rcpf(wl[w]);
    const float nunk = ws[WS_NUNK + w];
    const float ns2 = ws[WS_NS2 + a];
    const float qu = sqrtf(fmaf(nunk, nunk, -ns2));
    const float qA = ws[WS_QA + a];
    const float qB = ws[WS_QB + a];
    const float r15 = (qA - qu) * __builtin_amdgcn_rcpf(qA + qu);
    const float r16 = (qu - qB) * __builtin_amdgcn_rcpf(qu + qB);
    const float revu = 2.0f * qu * d_unk[0] * invlam;  // 2*delta of unknown layer, in revolutions

    float pr = ws[WS_R + (NIF - 1) * NA + a];  // rho at last interface (layers 31->32)
    float pi = 0.0f;

#pragma unroll
    for (int j = NINT - 1; j >= 0; --j) {
        // step j consumes layer (j+1)'s phase and interface j's r
        const float rev = (j == LAc) ? revu : ws[WS_QD2 + j * NA + a] * invlam;
        const float rj = (j == LAc) ? r15 : (j == LAc + 1) ? r16 : ws[WS_R + j * NA + a];
        const float f = __builtin_amdgcn_fractf(rev);
        const float s = __builtin_amdgcn_sinf(f);   // sin(2*pi*f)
        const float c = __builtin_amdgcn_cosf(f);   // cos(2*pi*f)
        // wv = rho * e^{2 i delta}
        const float wr = pr * c - pi * s;
        const float wi = pr * s + pi * c;
        const float nr = rj + wr, ni = wi;
        const float dr = fmaf(rj, wr, 1.0f), di = rj * wi;
        const float inv = __builtin_amdgcn_rcpf(fmaf(dr, dr, di * di));
        pr = (nr * dr + ni * di) * inv;
        pi = (ni * dr - nr * di) * inv;
    }
    if (idx < NW * NA) out[idx] = fmaf(pr, pr, pi * pi);
}

extern "C" void kernel_launch(void* const* d_in, const int* in_sizes, int n_in,
                              void* d_out, int out_size, void* d_ws, size_t ws_size,
                              hipStream_t stream) {
    const float* nk       = (const float*)d_in[0];  // refractive_index [350]
    const float* d_unk    = (const float*)d_in[1];  // unknown_layer_thickness [1]
    const float* d_above  = (const float*)d_in[2];  // thickness_above [15]
    const float* d_below  = (const float*)d_in[3];  // thickness_below [15]
    const float* fixed_n  = (const float*)d_in[4];  // fixed_n [32]
    const float* wl       = (const float*)d_in[5];  // wavelengths [2048]
    const float* angles   = (const float*)d_in[6];  // angles [128]
    float* out = (float*)d_out;
    float* ws  = (float*)d_ws;                      // ~42 KB of float scratch

    prep_kernel<<<1, 512, 0, stream>>>(nk, wl, fixed_n, d_above, d_below, angles, ws);
    tmm_kernel<<<(NW * NA) / 256, 256, 0, stream>>>(ws, d_unk, wl, out);
}

// Round 3
// 13.709 us; speedup vs baseline: 2.4035x; 1.3135x over previous
//
#include <hip/hip_runtime.h>
#include <math.h>

// Problem constants (mirror reference)
#define NPTS 350   // raw refractive_index samples
#define NSM  331   // after 'valid' conv with KS=20
#define KS   20    // gaussian kernel size
#define LAc  15    // layers above
#define NLAY 33    // total layers
#define NIF  32    // interfaces
#define NINT 31    // interior layers
#define NW   2048
#define NA   128
#define WPB  4     // wavelengths per block (2 per thread)

// ---------------------------------------------------------------------------
// Single fused kernel. Per block: 4 wavelengths x 128 angles, 256 threads,
// each thread runs 2 independent (w,a) recursions (ILP + table-read sharing).
//
// Math: backward recursive Fresnel (Parratt), division deferred:
//   N' = r_j*D + N*E,  D' = D + r_j*N*E,  E = e^{2 i delta_{j+1}}
// equals (r_j + rho E)/(1 + r_j rho E) with rho = N/D; R = |N|^2/|D|^2.
// All refractive indices real and > n0*sin(theta) => q, r real; only E complex.
// The 1/t interface scales of the reference cancel in M10/M00.
// Phases in revolutions: rev = 2 q d / lambda -> v_fract + v_sin/v_cos.
// ---------------------------------------------------------------------------
__global__ __launch_bounds__(256) void tmm_fused(
    const float* __restrict__ nk,
    const float* __restrict__ d_unk,
    const float* __restrict__ d_above,
    const float* __restrict__ d_below,
    const float* __restrict__ fixed_n,
    const float* __restrict__ wl,
    const float* __restrict__ angles,
    float* __restrict__ out)
{
    __shared__ float2 tab[NIF][NA];              // (r_j, 2*q_{j+1}*d_j)
    __shared__ float kern_s[KS];
    __shared__ float ns2_s[NA], qA_s[NA], qB_s[NA];

    const int tid = threadIdx.x;
    const int a = tid & (NA - 1);

    // ---- per-block setup ----
    if (tid < NA) {
        const float ang = angles[tid];
        const float nsin = fixed_n[0] * sinf(ang);
        const float ns2 = nsin * nsin;
        ns2_s[tid] = ns2;
        float q[NLAY];
#pragma unroll
        for (int l = 0; l < NLAY; ++l) {
            if (l == LAc + 1) continue;                      // unknown layer
            const float n = (l <= LAc) ? fixed_n[l] : fixed_n[l - 1];
            q[l] = sqrtf(fmaf(n, n, -ns2));
        }
        qA_s[tid] = q[LAc];
        qB_s[tid] = q[LAc + 2];
#pragma unroll
        for (int j = 0; j < NIF; ++j) {
            float r = 0.0f, qd2 = 0.0f;
            if (j != LAc && j != LAc + 1)
                r = (q[j] - q[j + 1]) * __builtin_amdgcn_rcpf(q[j] + q[j + 1]);
            if (j < NINT && j != LAc) {
                const float dj = (j < LAc) ? d_above[j] : d_below[j - LAc - 1];
                qd2 = 2.0f * q[j + 1] * dj;
            }
            tab[j][tid] = make_float2(r, qd2);
        }
    } else if (tid < NA + KS) {
        const int i = tid - NA;
        const float x = -10.0f + (float)i * (20.0f / 19.0f);
        kern_s[i] = expf(-(x * x) * (1.0f / 32.0f));         // amplitude cancels
    }
    __syncthreads();

    // gaussian-weight normalization (each thread, trivial)
    float ksum = 0.0f;
#pragma unroll
    for (int k = 0; k < KS; ++k) ksum += kern_s[k];
    const float kinv = __builtin_amdgcn_rcpf(ksum);

    // ---- per-thread chain setup (2 wavelengths) ----
    const int w0 = blockIdx.x * WPB + (tid >> 7);            // and w0+2
    const float l0 = wl[0];
    const float scale = (float)(NSM - 1) * __builtin_amdgcn_rcpf(wl[NW - 1] - l0);
    const float ns2 = ns2_s[a];
    const float qA = qA_s[a], qB = qB_s[a];
    const float du = d_unk[0];

    float invlam[2], revu[2], r15[2], r16[2];
    float Nr[2], Ni_[2], Dr[2], Di_[2];
    const float r31 = tab[NIF - 1][a].x;

#pragma unroll
    for (int ci = 0; ci < 2; ++ci) {
        const int w = w0 + 2 * ci;
        const float lam = wl[w];
        // smooth+interp n_unk at this wavelength (clamped linear on 331 grid)
        float pos = (lam - l0) * scale;
        pos = fminf(fmaxf(pos, 0.0f), (float)(NSM - 1));
        int i0 = (int)pos;
        if (i0 > NSM - 2) i0 = NSM - 2;
        const float f = pos - (float)i0;
        float s0 = 0.0f, s1 = 0.0f;
#pragma unroll
        for (int k = 0; k <= KS; ++k) {
            const float nv = nk[i0 + k];                     // broadcast in-wave
            if (k < KS) s0 = fmaf(nv, kern_s[k], s0);
            if (k > 0)  s1 = fmaf(nv, kern_s[k - 1], s1);
        }
        const float nunk = fmaf(f, s1 - s0, s0) * kinv;

        const float il = __builtin_amdgcn_rcpf(lam);
        invlam[ci] = il;
        const float qu = sqrtf(fmaf(nunk, nunk, -ns2));
        r15[ci] = (qA - qu) * __builtin_amdgcn_rcpf(qA + qu);
        r16[ci] = (qu - qB) * __builtin_amdgcn_rcpf(qu + qB);
        revu[ci] = 2.0f * qu * du * il;
        Nr[ci] = r31; Ni_[ci] = 0.0f; Dr[ci] = 1.0f; Di_[ci] = 0.0f;
    }

    // ---- main recursion, both chains per iteration ----
#pragma unroll
    for (int j = NINT - 1; j >= 0; --j) {
        const float2 tj = tab[j][a];
#pragma unroll
        for (int ci = 0; ci < 2; ++ci) {
            const float rev = (j == LAc) ? revu[ci] : tj.y * invlam[ci];
            const float rj = (j == LAc) ? r15[ci]
                           : (j == LAc + 1) ? r16[ci] : tj.x;
            const float fr = __builtin_amdgcn_fractf(rev);
            const float s = __builtin_amdgcn_sinf(fr);       // sin(2*pi*fr)
            const float c = __builtin_amdgcn_cosf(fr);
            const float NEr = Nr[ci] * c - Ni_[ci] * s;
            const float NEi = Nr[ci] * s + Ni_[ci] * c;
            Nr[ci] = fmaf(rj, Dr[ci], NEr);
            Ni_[ci] = fmaf(rj, Di_[ci], NEi);
            Dr[ci] = fmaf(rj, NEr, Dr[ci]);
            Di_[ci] = fmaf(rj, NEi, Di_[ci]);
        }
    }

#pragma unroll
    for (int ci = 0; ci < 2; ++ci) {
        const int w = w0 + 2 * ci;
        const float num = fmaf(Nr[ci], Nr[ci], Ni_[ci] * Ni_[ci]);
        const float den = fmaf(Dr[ci], Dr[ci], Di_[ci] * Di_[ci]);
        out[w * NA + a] = num * __builtin_amdgcn_rcpf(den);
    }
}

extern "C" void kernel_launch(void* const* d_in, const int* in_sizes, int n_in,
                              void* d_out, int out_size, void* d_ws, size_t ws_size,
                              hipStream_t stream) {
    const float* nk       = (const float*)d_in[0];  // refractive_index [350]
    const float* d_unk    = (const float*)d_in[1];  // unknown_layer_thickness [1]
    const float* d_above  = (const float*)d_in[2];  // thickness_above [15]
    const float* d_below  = (const float*)d_in[3];  // thickness_below [15]
    const float* fixed_n  = (const float*)d_in[4];  // fixed_n [32]
    const float* wl       = (const float*)d_in[5];  // wavelengths [2048]
    const float* angles   = (const float*)d_in[6];  // angles [128]
    float* out = (float*)d_out;

    tmm_fused<<<NW / WPB, 256, 0, stream>>>(nk, d_unk, d_above, d_below,
                                            fixed_n, wl, angles, out);
}

// Round 4
// 12.918 us; speedup vs baseline: 2.5508x; 1.0613x over previous
//
#include <hip/hip_runtime.h>
#include <math.h>

// Problem constants (mirror reference)
#define NPTS 350   // raw refractive_index samples
#define NSM  331   // after 'valid' conv with KS=20
#define KS   20    // gaussian kernel size
#define LAc  15    // layers above
#define NLAY 33    // total layers
#define NIF  32    // interfaces
#define NINT 31    // interior layers
#define NW   2048
#define NA   128
#define WPB  4     // wavelengths per block (2 chains per thread)

// ---------------------------------------------------------------------------
// Single fused kernel, no LDS, no __syncthreads. One thread = one angle x two
// wavelengths (w0, w0+2). Per-thread, in registers: gaussian-smoothed n_unk
// (21 broadcast loads + 40 FMA per chain), per-angle q/r/phase tables
// (33 sqrt + 30 rcp, shared by both chains), then the 31-step backward
// recursive Fresnel (Parratt) with deferred division:
//   N' = r_j*D + N*E,  D' = D + r_j*N*E,  E = e^{2 i delta_{j+1}}
//   R = |N|^2 / |D|^2   (== |M10/M00|^2 of the reference matrix chain; the
//                        1/t interface scales cancel)
// All n real and > n0*sin(theta) => q, r real; only E complex.
// Phases in revolutions: rev = 2 q d / lambda -> v_fract + v_sin/v_cos.
// ---------------------------------------------------------------------------
__global__ __launch_bounds__(256, 2) void tmm_fused(
    const float* __restrict__ nk,
    const float* __restrict__ d_unk,
    const float* __restrict__ d_above,
    const float* __restrict__ d_below,
    const float* __restrict__ fixed_n,
    const float* __restrict__ wl,
    const float* __restrict__ angles,
    float* __restrict__ out)
{
    const int tid = threadIdx.x;
    const int a = tid & (NA - 1);
    const int w0 = blockIdx.x * WPB + (tid >> 7);   // chains: w0, w0+2

    // ---- issue global reads early (lam -> i0 -> nk loads on critical path)
    const float l0 = wl[0];
    const float lN = wl[NW - 1];
    const float lam[2] = { wl[w0], wl[w0 + 2] };
    const float ang = angles[a];
    const float du = d_unk[0];

    // gaussian weights (runtime, fast exp; amplitude cancels in normalization)
    float kern[KS];
    float ksum = 0.0f;
#pragma unroll
    for (int k = 0; k < KS; ++k) {
        const float x = -10.0f + (float)k * (20.0f / 19.0f);
        kern[k] = __expf(-(x * x) * (1.0f / 32.0f));
        ksum += kern[k];
    }
    const float kinv = __builtin_amdgcn_rcpf(ksum);

    // smooth+interp n_unk for both chains (clamped linear on the 331 grid)
    const float scale = (float)(NSM - 1) * __builtin_amdgcn_rcpf(lN - l0);
    float nunk[2], invlam[2];
#pragma unroll
    for (int ci = 0; ci < 2; ++ci) {
        float pos = (lam[ci] - l0) * scale;
        pos = fminf(fmaxf(pos, 0.0f), (float)(NSM - 1));
        int i0 = (int)pos;
        if (i0 > NSM - 2) i0 = NSM - 2;
        const float f = pos - (float)i0;
        float s0 = 0.0f, s1 = 0.0f;
#pragma unroll
        for (int k = 0; k <= KS; ++k) {
            const float nv = nk[i0 + k];                 // broadcast in-wave
            if (k < KS) s0 = fmaf(nv, kern[k], s0);
            if (k > 0)  s1 = fmaf(nv, kern[k - 1], s1);
        }
        nunk[ci] = fmaf(f, s1 - s0, s0) * kinv;
        invlam[ci] = __builtin_amdgcn_rcpf(lam[ci]);
    }

    // ---- per-angle tables, in registers (shared by both chains) ----
    // sin(ang), ang in [0,1] rad -> revolutions in [0,0.16], no fract needed
    const float nsin = fixed_n[0] * __builtin_amdgcn_sinf(ang * 0.15915494309189535f);
    const float ns2 = nsin * nsin;

    float q[NLAY];
#pragma unroll
    for (int l = 0; l < NLAY; ++l) {
        if (l == LAc + 1) continue;                      // unknown layer
        const float n = (l <= LAc) ? fixed_n[l] : fixed_n[l - 1];
        q[l] = sqrtf(fmaf(n, n, -ns2));
    }

    float rt[NIF];     // interface r (j != 15,16)
    float qd2[NINT];   // 2*q_{j+1}*d_j  (j != 15)
#pragma unroll
    for (int j = 0; j < NIF; ++j) {
        if (j == LAc || j == LAc + 1) { rt[j] = 0.0f; continue; }
        rt[j] = (q[j] - q[j + 1]) * __builtin_amdgcn_rcpf(q[j] + q[j + 1]);
    }
#pragma unroll
    for (int j = 0; j < NINT; ++j) {
        if (j == LAc) { qd2[j] = 0.0f; continue; }
        const float dj = (j < LAc) ? d_above[j] : d_below[j - LAc - 1];
        qd2[j] = 2.0f * q[j + 1] * dj;
    }

    // ---- per-chain unknown-layer quantities ----
    float r15[2], r16[2], revu[2];
    float Nr[2], Ni_[2], Dr[2], Di_[2];
#pragma unroll
    for (int ci = 0; ci < 2; ++ci) {
        const float qu = sqrtf(fmaf(nunk[ci], nunk[ci], -ns2));
        r15[ci] = (q[LAc] - qu) * __builtin_amdgcn_rcpf(q[LAc] + qu);
        r16[ci] = (qu - q[LAc + 2]) * __builtin_amdgcn_rcpf(qu + q[LAc + 2]);
        revu[ci] = 2.0f * qu * du * invlam[ci];
        Nr[ci] = rt[NIF - 1]; Ni_[ci] = 0.0f;
        Dr[ci] = 1.0f;        Di_[ci] = 0.0f;
    }

    // ---- main recursion, both chains per iteration ----
#pragma unroll
    for (int j = NINT - 1; j >= 0; --j) {
#pragma unroll
        for (int ci = 0; ci < 2; ++ci) {
            const float rev = (j == LAc) ? revu[ci] : qd2[j] * invlam[ci];
            const float rj = (j == LAc) ? r15[ci]
                           : (j == LAc + 1) ? r16[ci] : rt[j];
            const float fr = __builtin_amdgcn_fractf(rev);
            const float s = __builtin_amdgcn_sinf(fr);    // sin(2*pi*fr)
            const float c = __builtin_amdgcn_cosf(fr);
            const float NEr = Nr[ci] * c - Ni_[ci] * s;
            const float NEi = Nr[ci] * s + Ni_[ci] * c;
            Nr[ci]  = fmaf(rj, Dr[ci], NEr);
            Ni_[ci] = fmaf(rj, Di_[ci], NEi);
            Dr[ci]  = fmaf(rj, NEr, Dr[ci]);
            Di_[ci] = fmaf(rj, NEi, Di_[ci]);
        }
    }

#pragma unroll
    for (int ci = 0; ci < 2; ++ci) {
        const int w = w0 + 2 * ci;
        const float num = fmaf(Nr[ci], Nr[ci], Ni_[ci] * Ni_[ci]);
        const float den = fmaf(Dr[ci], Dr[ci], Di_[ci] * Di_[ci]);
        out[w * NA + a] = num * __builtin_amdgcn_rcpf(den);
    }
}

extern "C" void kernel_launch(void* const* d_in, const int* in_sizes, int n_in,
                              void* d_out, int out_size, void* d_ws, size_t ws_size,
                              hipStream_t stream) {
    const float* nk       = (const float*)d_in[0];  // refractive_index [350]
    const float* d_unk    = (const float*)d_in[1];  // unknown_layer_thickness [1]
    const float* d_above  = (const float*)d_in[2];  // thickness_above [15]
    const float* d_below  = (const float*)d_in[3];  // thickness_below [15]
    const float* fixed_n  = (const float*)d_in[4];  // fixed_n [32]
    const float* wl       = (const float*)d_in[5];  // wavelengths [2048]
    const float* angles   = (const float*)d_in[6];  // angles [128]
    float* out = (float*)d_out;

    tmm_fused<<<NW / WPB, 256, 0, stream>>>(nk, d_unk, d_above, d_below,
                                            fixed_n, wl, angles, out);
}

// Round 5
// 12.519 us; speedup vs baseline: 2.6320x; 1.0318x over previous
//
#include <hip/hip_runtime.h>
#include <math.h>

// Problem constants (mirror reference)
#define NPTS 350   // raw refractive_index samples
#define NSM  331   // after 'valid' conv with KS=20
#define KS   20    // gaussian kernel size
#define LAc  15    // layers above
#define NLAY 33    // total layers
#define NIF  32    // interfaces
#define NINT 31    // interior layers
#define NW   2048
#define NA   128
#define WPB  4     // wavelengths per block (2 chains per thread)

// ---------------------------------------------------------------------------
// Single fused kernel, no LDS, no __syncthreads. One thread = one angle x two
// wavelengths (w0, w0+2). Gaussian-smoothed n_unk in registers (transient
// 20-reg kernel weights, dead before the q-table is built), per-angle q table
// in registers, and interface r / phase coefficients computed IN-LOOP (each is
// consumed exactly once -> no rt[32]/qd2[31] arrays, ~63 VGPRs saved, no
// spill risk under launch_bounds(256,2)).
//
// Math: backward recursive Fresnel (Parratt) with deferred division:
//   N' = r_j*D + N*E,  D' = D + r_j*N*E,  E = e^{2 i delta_{j+1}}
//   R = |N|^2/|D|^2  (== |M10/M00|^2 of the reference chain; 1/t scales cancel)
// All n real and > n0*sin(theta) => q, r real; only E complex.
// Phases in revolutions: rev = 2 q d / lambda -> v_fract + v_sin/v_cos.
// ---------------------------------------------------------------------------
__global__ __launch_bounds__(256, 2) void tmm_fused(
    const float* __restrict__ nk,
    const float* __restrict__ d_unk,
    const float* __restrict__ d_above,
    const float* __restrict__ d_below,
    const float* __restrict__ fixed_n,
    const float* __restrict__ wl,
    const float* __restrict__ angles,
    float* __restrict__ out)
{
    const int tid = threadIdx.x;
    const int a = tid & (NA - 1);
    const int w0 = blockIdx.x * WPB + (tid >> 7);   // chains: w0, w0+2

    const float l0 = wl[0];
    const float lN = wl[NW - 1];
    const float lam[2] = { wl[w0], wl[w0 + 2] };
    const float ang = angles[a];
    const float du = d_unk[0];

    // gaussian weights (transient registers; amplitude cancels in norm)
    float kern[KS];
    float ksum = 0.0f;
#pragma unroll
    for (int k = 0; k < KS; ++k) {
        const float x = -10.0f + (float)k * (20.0f / 19.0f);
        kern[k] = __expf(-(x * x) * (1.0f / 32.0f));
        ksum += kern[k];
    }
    const float kinv = __builtin_amdgcn_rcpf(ksum);

    // smooth+interp n_unk for both chains (clamped linear on the 331 grid)
    const float scale = (float)(NSM - 1) * __builtin_amdgcn_rcpf(lN - l0);
    float nunk[2], invlam[2];
#pragma unroll
    for (int ci = 0; ci < 2; ++ci) {
        float pos = (lam[ci] - l0) * scale;
        pos = fminf(fmaxf(pos, 0.0f), (float)(NSM - 1));
        int i0 = (int)pos;
        if (i0 > NSM - 2) i0 = NSM - 2;
        const float f = pos - (float)i0;
        float s0 = 0.0f, s1 = 0.0f;
#pragma unroll
        for (int k = 0; k <= KS; ++k) {
            const float nv = nk[i0 + k];                 // broadcast in-wave
            if (k < KS) s0 = fmaf(nv, kern[k], s0);
            if (k > 0)  s1 = fmaf(nv, kern[k - 1], s1);
        }
        nunk[ci] = fmaf(f, s1 - s0, s0) * kinv;
        invlam[ci] = __builtin_amdgcn_rcpf(lam[ci]);
    }
    // kern[] dead from here -> registers reused for q[]

    // ---- per-angle q table, in registers (shared by both chains) ----
    // ang in [0,1] rad -> revolutions in [0,0.16]
    const float nsin = fixed_n[0] * __builtin_amdgcn_sinf(ang * 0.15915494309189535f);
    const float ns2 = nsin * nsin;

    float q[NLAY];
#pragma unroll
    for (int l = 0; l < NLAY; ++l) {
        if (l == LAc + 1) continue;                      // unknown layer
        const float n = (l <= LAc) ? fixed_n[l] : fixed_n[l - 1];
        q[l] = sqrtf(fmaf(n, n, -ns2));
    }

    // ---- per-chain unknown-layer quantities ----
    float r15[2], r16[2], revu[2];
    float Nr[2], Ni_[2], Dr[2], Di_[2];
    const float rlast = (q[NIF - 1] - q[NIF]) * __builtin_amdgcn_rcpf(q[NIF - 1] + q[NIF]);
#pragma unroll
    for (int ci = 0; ci < 2; ++ci) {
        const float qu = sqrtf(fmaf(nunk[ci], nunk[ci], -ns2));
        r15[ci] = (q[LAc] - qu) * __builtin_amdgcn_rcpf(q[LAc] + qu);
        r16[ci] = (qu - q[LAc + 2]) * __builtin_amdgcn_rcpf(qu + q[LAc + 2]);
        revu[ci] = 2.0f * qu * du * invlam[ci];
        Nr[ci] = rlast; Ni_[ci] = 0.0f;
        Dr[ci] = 1.0f;  Di_[ci] = 0.0f;
    }

    // ---- main recursion; r_j and phase coeff computed in-loop, shared ----
#pragma unroll
    for (int j = NINT - 1; j >= 0; --j) {
        float rj_s = 0.0f, tq = 0.0f;
        if (j != LAc && j != LAc + 1)
            rj_s = (q[j] - q[j + 1]) * __builtin_amdgcn_rcpf(q[j] + q[j + 1]);
        if (j != LAc) {
            const float dj = (j < LAc) ? d_above[j] : d_below[j - LAc - 1];
            tq = q[j + 1] * (2.0f * dj);                 // 2*q_{j+1}*d_j
        }
#pragma unroll
        for (int ci = 0; ci < 2; ++ci) {
            const float rev = (j == LAc) ? revu[ci] : tq * invlam[ci];
            const float rj = (j == LAc) ? r15[ci]
                           : (j == LAc + 1) ? r16[ci] : rj_s;
            const float fr = __builtin_amdgcn_fractf(rev);
            const float s = __builtin_amdgcn_sinf(fr);   // sin(2*pi*fr)
            const float c = __builtin_amdgcn_cosf(fr);
            const float NEr = Nr[ci] * c - Ni_[ci] * s;
            const float NEi = Nr[ci] * s + Ni_[ci] * c;
            Nr[ci]  = fmaf(rj, Dr[ci], NEr);
            Ni_[ci] = fmaf(rj, Di_[ci], NEi);
            Dr[ci]  = fmaf(rj, NEr, Dr[ci]);
            Di_[ci] = fmaf(rj, NEi, Di_[ci]);
        }
    }

#pragma unroll
    for (int ci = 0; ci < 2; ++ci) {
        const int w = w0 + 2 * ci;
        const float num = fmaf(Nr[ci], Nr[ci], Ni_[ci] * Ni_[ci]);
        const float den = fmaf(Dr[ci], Dr[ci], Di_[ci] * Di_[ci]);
        out[w * NA + a] = num * __builtin_amdgcn_rcpf(den);
    }
}

extern "C" void kernel_launch(void* const* d_in, const int* in_sizes, int n_in,
                              void* d_out, int out_size, void* d_ws, size_t ws_size,
                              hipStream_t stream) {
    const float* nk       = (const float*)d_in[0];  // refractive_index [350]
    const float* d_unk    = (const float*)d_in[1];  // unknown_layer_thickness [1]
    const float* d_above  = (const float*)d_in[2];  // thickness_above [15]
    const float* d_below  = (const float*)d_in[3];  // thickness_below [15]
    const float* fixed_n  = (const float*)d_in[4];  // fixed_n [32]
    const float* wl       = (const float*)d_in[5];  // wavelengths [2048]
    const float* angles   = (const float*)d_in[6];  // angles [128]
    float* out = (float*)d_out;

    tmm_fused<<<NW / WPB, 256, 0, stream>>>(nk, d_unk, d_above, d_below,
                                            fixed_n, wl, angles, out);
}